// Round 7
// baseline (19675.395 us; speedup 1.0000x reference)
//
#include <hip/hip_runtime.h>
#include <cmath>

// LIF_complex round 12: 256 blocks x 8 rows -- halve the compute span,
// preserve the summation tree exactly.
// Round 11 (5-deep pipelined poll) regressed 15.0->17.65 ms: compiler
// emits one vmcnt(0) drain over all 5 in-flight loads, so each retry
// waited for the LAST load (+770cy issue stagger), lengthening the period
// while 5x-ing same-line MALL traffic. Hop-attack ledger: r9 +1.3ms,
// r10 +0.3ms, r11 +2.9ms -> the publish->observe hop (~3000cy) is
// deterministic, contention-light latency; stop attacking it.
// r8's residual budget: hop ~3000 + compute/sync ~1300 cy. The
// addressable term is the ~900cy post-bar1 issue span on only 128 active
// CUs (half the machine idle). This round: 256 blocks x 8 rows, 1 block/CU
// on ALL 256 CUs; per-thread dot halves (2 rows x 8 cols); span ~450cy.
// Occupancy must jump 24.9 -> ~49.8% (signature the split engaged).
// Bit-exactness preserved by construction: per-row tree is EXACTLY
// pairwise4(DPP64(chain8)) as in r8 -- a wave owns rows {r, r+4} for one
// 512-col group; update tree (p0+p1)+(p2+p3) unchanged; decay/select,
// branch-free bit-exact sigmoid (r10), publish order unchanged.
// absmax must stay exactly 0.001953125 (bit-exactness canary).
// Poll: r8's proven simple retry, now waves 0-3 over 256 padded slots
// (4x machine-wide poll lines; r10 measured 2x ~= +2% -> acceptable).
// Tag protocol & overwrite-safety induction unchanged (bar1 certifies all
// 256 slots observed at t-1; publish t follows bar2(t)).

#define T_STEPS 8192
#define NN      2048
#define NBLK    256
#define NTHR    1024
#define RPB     8
#define DUMP    64
#define NSLOT   256
#define PADU    16   // u64s per slot: one 128 B line per block

typedef unsigned long long u64;

__device__ __forceinline__ float stable_sigmoid(float x) {
    // Bit-exact, branch-free form of:
    //   x>=0 ? 1/(1+expf(-x)) : expf(x)/(1+expf(x))
    float E   = expf(-fabsf(x));
    float den = 1.0f + E;
    float num = (x >= 0.0f) ? 1.0f : E;
    return num / den;
}

// acc += dpp_shuffled(acc); masked-out / out-of-bounds lanes add 0.0f.
// Only lane 63's final value is consumed.
#define DPP_ADD(acc, ctrl, rmask)                                         \
    acc += __int_as_float(__builtin_amdgcn_update_dpp(                    \
        0, __float_as_int(acc), ctrl, rmask, 0xF, true));

// Full 64-lane sum (bitwise == xor-butterfly result), answer in lane 63.
#define WAVE_RED(acc)            \
    DPP_ADD(acc, 0x111, 0xF)     \
    DPP_ADD(acc, 0x112, 0xF)     \
    DPP_ADD(acc, 0x114, 0xF)     \
    DPP_ADD(acc, 0x118, 0xF)     \
    DPP_ADD(acc, 0x142, 0xA)     \
    DPP_ADD(acc, 0x143, 0xC)

__global__ __launch_bounds__(NTHR, 2) void lif_kernel(
    const float* __restrict__ x_in,    // [T, N]
    const float* __restrict__ w,       // [N, N]
    const float* __restrict__ v_rest,  // [N]
    const float* __restrict__ tau_m,   // [N]
    const float* __restrict__ tau_g,   // [N]
    const float* __restrict__ pre_cp,  // [1]
    const float* __restrict__ post_cp, // [1]
    const float* __restrict__ v0,      // [N]
    const float* __restrict__ g0,      // [N]
    float* __restrict__ out,           // [2, T, N]
    u64* __restrict__ slots)           // [2, NSLOT, PADU] tagged spike slots
{
    __shared__ unsigned sbits[NSLOT];         // relayed spike bits, step t-1
    __shared__ float preduce[2][4][RPB];      // double-buffered partials
    __shared__ float vbuf[2][DUMP][RPB];      // double-buffered dump window
    __shared__ float sbuf[2][DUMP][RPB];

    const int tid = threadIdx.x;
    const int b   = blockIdx.x;
    const int wv  = tid >> 6;
    const int rlo = wv >> 2;           // rows rlo and rlo+4 of this block's 8
    const int j   = wv & 3;            // col group (512 cols)
    const int k   = tid & 63;          // lane

    // ---- w tile into named registers: rows b*8+rlo, b*8+rlo+4,
    //      cols 512j+8k..+7
    const float* wbase = w + (size_t)(b * RPB + rlo) * NN + 512 * j;
    const float4* rl = (const float4*)(wbase);
    const float4* rh = (const float4*)(wbase + 4 * NN);
    const float4 wla = rl[2 * k], wlb = rl[2 * k + 1];
    const float4 wha = rh[2 * k], whb = rh[2 * k + 1];

    // ---- this thread's 8 g columns live in registers for the whole run
    const int c0 = 512 * j + 8 * k;    // first owned column
    float4 ga = ((const float4*)(g0 + c0))[0];
    float4 gb = ((const float4*)(g0 + c0))[1];
    const float4 tga = ((const float4*)(tau_g + c0))[0];
    const float4 tgb = ((const float4*)(tau_g + c0))[1];
    const float4 rga = make_float4(1.0f / tga.x, 1.0f / tga.y,
                                   1.0f / tga.z, 1.0f / tga.w);
    const float4 rgb = make_float4(1.0f / tgb.x, 1.0f / tgb.y,
                                   1.0f / tgb.z, 1.0f / tgb.w);
    const int slot_i = c0 >> 3;        // owning block of these 8 cols
                                       // (c0 % 8 == 0 -> bit offset 0)

    const float pre_c  = pre_cp[0];
    const float post_c = post_cp[0];

    // ---- neuron v-state lives in wave 0, lanes 0..7
    float vr = 0.f, rtm = 0.f, v = 0.f;
    if (tid < RPB) {
        const int n = b * RPB + tid;
        vr  = v_rest[n];
        rtm = 1.0f / tau_m[n];         // exact for tau_m = 4
        v   = v0[n];
    }

    for (int t = 0; t < T_STEPS; ++t) {
        // x prefetch (consumed by wave 0 after barrier 2)
        float x = 0.0f;
        if (tid < RPB) x = x_in[(size_t)t * NN + b * RPB + tid];

        float4 da = ga, db = gb;
        if (t != 0) {
            // speculative decay: independent of the incoming spike bits.
            // fma(-r,g,g) == g - g/tau (exact for tau_g = 2).
            da.x = fmaf(-rga.x, ga.x, ga.x); da.y = fmaf(-rga.y, ga.y, ga.y);
            da.z = fmaf(-rga.z, ga.z, ga.z); da.w = fmaf(-rga.w, ga.w, ga.w);
            db.x = fmaf(-rgb.x, gb.x, gb.x); db.y = fmaf(-rgb.y, gb.y, gb.y);
            db.z = fmaf(-rgb.z, gb.z, gb.z); db.w = fmaf(-rgb.w, gb.w, gb.w);

            // ---- poll spikes(t-1): waves 0-3, one padded line per lane
            // (256 slots), r8's proven simple retry loop
            if (wv < 4) {
                const int s = (wv << 6) | k;
                const u64* sl = slots +
                    ((size_t)((t - 1) & 1) * NSLOT + s) * PADU;
                const unsigned want = (unsigned)(t - 1);
                u64 A = __hip_atomic_load(sl, __ATOMIC_RELAXED,
                                          __HIP_MEMORY_SCOPE_AGENT);
                while ((unsigned)(A >> 32) != want) {
                    __builtin_amdgcn_s_sleep(1);
                    A = __hip_atomic_load(sl, __ATOMIC_RELAXED,
                                          __HIP_MEMORY_SCOPE_AGENT);
                }
                sbits[s] = (unsigned)A;   // low 8 bits = block s's spikes
            }
        }
        __syncthreads();  // barrier 1: sbits complete; certifies all 256
                          // slots observed at tag t-1 block-wide

        if (t != 0) {
            const unsigned bits = sbits[slot_i];  // stride-1, conflict-free
            ga.x = (bits &   1u) ? 1.0f : da.x;
            ga.y = (bits &   2u) ? 1.0f : da.y;
            ga.z = (bits &   4u) ? 1.0f : da.z;
            ga.w = (bits &   8u) ? 1.0f : da.w;
            gb.x = (bits &  16u) ? 1.0f : db.x;
            gb.y = (bits &  32u) ? 1.0f : db.y;
            gb.z = (bits &  64u) ? 1.0f : db.z;
            gb.w = (bits & 128u) ? 1.0f : db.w;
        }

        // ---- dot: rows {rlo, rlo+4} x cols 512j+8k..+7, w and g in regs.
        // Per-row operand order identical to r8: chain8 -> DPP64 -> pair4.
        float a0 = 0.f, a1 = 0.f;
#define ROWFMA(acc, wa, wb)                                       \
        acc = fmaf(wa.x, ga.x, acc); acc = fmaf(wa.y, ga.y, acc); \
        acc = fmaf(wa.z, ga.z, acc); acc = fmaf(wa.w, ga.w, acc); \
        acc = fmaf(wb.x, gb.x, acc); acc = fmaf(wb.y, gb.y, acc); \
        acc = fmaf(wb.z, gb.z, acc); acc = fmaf(wb.w, gb.w, acc);
        ROWFMA(a0, wla, wlb)
        ROWFMA(a1, wha, whb)
#undef ROWFMA
        // 64-lane sum via DPP (VALU pipe only), result in lane 63
        WAVE_RED(a0)
        WAVE_RED(a1)
        if (k == 63) {
            preduce[t & 1][j][rlo]     = a0;
            preduce[t & 1][j][rlo + 4] = a1;
        }
        __syncthreads();  // barrier 2: preduce complete

        // ---- neuron update + spike-bit publish (wave 0, lanes 0..7)
        if (tid < RPB) {
            const float* pr = (const float*)preduce[t & 1];
            float u = (pr[tid] + pr[tid + RPB]) +
                      (pr[tid + 2 * RPB] + pr[tid + 3 * RPB]);
            float I = post_c * stable_sigmoid(pre_c * (u + x));
            v = v + (vr - v + I) * rtm;
            bool spk = (v >= 30.0f);
            u64 bal = __ballot(spk);   // bits 0..7 = this block's spikes
            if (tid == 0) {
                u64 pk = ((u64)(unsigned)t << 32) | (bal & 0xFFull);
                __hip_atomic_store(slots + ((size_t)(t & 1) * NSLOT + b) * PADU,
                                   pk, __ATOMIC_RELAXED,
                                   __HIP_MEMORY_SCOPE_AGENT);
            }
            // keep the expensive soft-sigmoid/LDS writes BELOW the publish
            __builtin_amdgcn_sched_barrier(0);
            float soft = stable_sigmoid(v - 30.0f);   // pre-reset v
            v = spk ? vr : v;
            vbuf[(t >> 6) & 1][t & (DUMP - 1)][tid] = v;
            sbuf[(t >> 6) & 1][t & (DUMP - 1)][tid] = soft;
        }

        // ---- output dump (after the update so it never delays the
        // publish): window closed 64 steps ago, opposite buffer
        if ((t & (DUMP - 1)) == 0 && t != 0 && tid < DUMP * RPB) {
            const int bb = ((t >> 6) & 1) ^ 1;
            const int t0 = t - DUMP;
            const int s  = tid >> 3;
            const int rr = tid & 7;
            size_t o = (size_t)(t0 + s) * NN + b * RPB + rr;
            out[o] = vbuf[bb][s][rr];
            out[(size_t)T_STEPS * NN + o] = sbuf[bb][s][rr];
        }
        // no trailing barrier: next sbits write is by waves 0-3 after THEIR
        // barrier-2 arrival; preduce alternates parity; vbuf half-buffers
        // alternate every 64 steps; slot overwrite is 2 steps away.
    }

    // ---- final window dump
    __syncthreads();
    if (tid < DUMP * RPB) {
        const int bb = ((T_STEPS - DUMP) >> 6) & 1;
        const int t0 = T_STEPS - DUMP;
        const int s  = tid >> 3;
        const int rr = tid & 7;
        size_t o = (size_t)(t0 + s) * NN + b * RPB + rr;
        out[o] = vbuf[bb][s][rr];
        out[(size_t)T_STEPS * NN + o] = sbuf[bb][s][rr];
    }
}

extern "C" void kernel_launch(void* const* d_in, const int* in_sizes, int n_in,
                              void* d_out, int out_size, void* d_ws, size_t ws_size,
                              hipStream_t stream) {
    const float* x_in   = (const float*)d_in[0];
    const float* w      = (const float*)d_in[1];
    const float* v_rest = (const float*)d_in[2];
    const float* tau_m  = (const float*)d_in[3];
    const float* tau_g  = (const float*)d_in[4];
    const float* pre_c  = (const float*)d_in[5];
    const float* post_c = (const float*)d_in[6];
    const float* v0     = (const float*)d_in[7];
    const float* g0     = (const float*)d_in[8];
    float* out = (float*)d_out;

    u64* slots = (u64*)d_ws;  // [2, NSLOT, PADU] = 64 KB

    // tag 0xFFFFFFFF never matches any t in [0, 8192)
    hipMemsetAsync(slots, 0xFF, 2 * NSLOT * PADU * sizeof(u64), stream);

    void* args[] = {
        (void*)&x_in, (void*)&w, (void*)&v_rest, (void*)&tau_m, (void*)&tau_g,
        (void*)&pre_c, (void*)&post_c, (void*)&v0, (void*)&g0,
        (void*)&out, (void*)&slots
    };
    hipLaunchCooperativeKernel((void*)lif_kernel, dim3(NBLK), dim3(NTHR),
                               args, 0, stream);
}

// Round 8
// 14905.655 us; speedup vs baseline: 1.3200x; 1.3200x over previous
//
#include <hip/hip_runtime.h>
#include <cmath>

// LIF_complex round 13: revert to round 8 (best measured: 14.68 ms) +
// branch-free bit-exact sigmoid on the updater critical path.
// Round-12 post-mortem: 256 blocks regressed to 19.6 ms. FETCH decomposition
// proved the exchange cost scales with NSLOT x XCD invalidation/refetch
// events (r8: 537 MB = 128 lines x 64 B x 8 XCDs x 8192 steps; r12 doubled
// it), so more blocks = linearly more coherence events = slower steps.
// Hop-attack ledger: r9 arrival-driven +1.3 ms, r10 cohort-B +0.3, r11
// deep-poll +2.9, r12 scale-out +4.9. r8's shape (128 blocks, 128
// single-writer padded lines, 2-wave relay, 2 barriers, DPP reduction) is
// the measured optimum; this round restores it byte-for-byte except:
//  - stable_sigmoid is the branch-free form (ONE expf + ONE div + cndmask
//    instead of both divergent sides for the straddling updater lanes;
//    proven bit-exact in r10: -x == -|x| for x>=0, x == -|x| for x<0,
//    identical op order per branch). ~60-100 cy off the serial post-bar2
//    publish chain.
// Everything else (dot, chain8 -> DPP64 -> pairwise4 tree, publish-before-
// soft-sigmoid order, tag protocol, overwrite-safety induction) is r8.
// absmax must stay exactly 0.001953125 (bit-exactness canary).

#define T_STEPS 8192
#define NN      2048
#define NBLK    128
#define NTHR    1024
#define RPB     16
#define DUMP    64
#define NSLOT   128
#define PADU    16   // u64s per slot: one 128 B line per block

typedef unsigned long long u64;

__device__ __forceinline__ float stable_sigmoid(float x) {
    // Bit-exact, branch-free form of:
    //   x>=0 ? 1/(1+expf(-x)) : expf(x)/(1+expf(x))
    float E   = expf(-fabsf(x));
    float den = 1.0f + E;
    float num = (x >= 0.0f) ? 1.0f : E;
    return num / den;
}

// acc += dpp_shuffled(acc); masked-out / out-of-bounds lanes add 0.0f.
// Only lane 63's final value is consumed.
#define DPP_ADD(acc, ctrl, rmask)                                         \
    acc += __int_as_float(__builtin_amdgcn_update_dpp(                    \
        0, __float_as_int(acc), ctrl, rmask, 0xF, true));

// Full 64-lane sum (bitwise == xor-butterfly result), answer in lane 63.
#define WAVE_RED(acc)            \
    DPP_ADD(acc, 0x111, 0xF)     \
    DPP_ADD(acc, 0x112, 0xF)     \
    DPP_ADD(acc, 0x114, 0xF)     \
    DPP_ADD(acc, 0x118, 0xF)     \
    DPP_ADD(acc, 0x142, 0xA)     \
    DPP_ADD(acc, 0x143, 0xC)

__global__ __launch_bounds__(NTHR, 2) void lif_kernel(
    const float* __restrict__ x_in,    // [T, N]
    const float* __restrict__ w,       // [N, N]
    const float* __restrict__ v_rest,  // [N]
    const float* __restrict__ tau_m,   // [N]
    const float* __restrict__ tau_g,   // [N]
    const float* __restrict__ pre_cp,  // [1]
    const float* __restrict__ post_cp, // [1]
    const float* __restrict__ v0,      // [N]
    const float* __restrict__ g0,      // [N]
    float* __restrict__ out,           // [2, T, N]
    u64* __restrict__ slots)           // [2, NSLOT, PADU] tagged spike slots
{
    __shared__ unsigned sbits[NSLOT];         // relayed spike bits, step t-1
    __shared__ float preduce[2][4][RPB];      // double-buffered partials
    __shared__ float vbuf[2][DUMP][RPB];      // double-buffered dump window
    __shared__ float sbuf[2][DUMP][RPB];

    const int tid = threadIdx.x;
    const int b   = blockIdx.x;
    const int wv  = tid >> 6;
    const int i   = wv & 3;            // row group (4 rows)
    const int j   = wv >> 2;           // col group (512 cols)
    const int k   = tid & 63;          // lane

    // ---- w tile into named registers: rows b*16+4i..+3, cols 512j+8k..+7
    const float* wbase = w + (size_t)(b * RPB + 4 * i) * NN + 512 * j;
    const float4* r0 = (const float4*)(wbase);
    const float4* r1 = (const float4*)(wbase + NN);
    const float4* r2 = (const float4*)(wbase + 2 * NN);
    const float4* r3 = (const float4*)(wbase + 3 * NN);
    const float4 w0a = r0[2 * k], w0b = r0[2 * k + 1];
    const float4 w1a = r1[2 * k], w1b = r1[2 * k + 1];
    const float4 w2a = r2[2 * k], w2b = r2[2 * k + 1];
    const float4 w3a = r3[2 * k], w3b = r3[2 * k + 1];

    // ---- this thread's 8 g columns live in registers for the whole run
    const int c0 = 512 * j + 8 * k;    // first owned column
    float4 ga = ((const float4*)(g0 + c0))[0];
    float4 gb = ((const float4*)(g0 + c0))[1];
    const float4 tga = ((const float4*)(tau_g + c0))[0];
    const float4 tgb = ((const float4*)(tau_g + c0))[1];
    const float4 rga = make_float4(1.0f / tga.x, 1.0f / tga.y,
                                   1.0f / tga.z, 1.0f / tga.w);
    const float4 rgb = make_float4(1.0f / tgb.x, 1.0f / tgb.y,
                                   1.0f / tgb.z, 1.0f / tgb.w);
    const int slot_i  = c0 >> 4;       // owning block of these 8 cols
    const int bitbase = c0 & 15;       // 0 or 8: bit offset in that slot

    const float pre_c  = pre_cp[0];
    const float post_c = post_cp[0];

    // ---- neuron v-state lives in wave 0, lanes 0..15
    float vr = 0.f, rtm = 0.f, v = 0.f;
    if (tid < RPB) {
        const int n = b * RPB + tid;
        vr  = v_rest[n];
        rtm = 1.0f / tau_m[n];         // exact for tau_m = 4
        v   = v0[n];
    }

    for (int t = 0; t < T_STEPS; ++t) {
        // x prefetch (consumed by wave 0 after barrier 2)
        float x = 0.0f;
        if (tid < RPB) x = x_in[(size_t)t * NN + b * RPB + tid];

        float4 da = ga, db = gb;
        if (t != 0) {
            // speculative decay: independent of the incoming spike bits.
            // fma(-r,g,g) == g - g/tau (exact for tau_g = 2).
            da.x = fmaf(-rga.x, ga.x, ga.x); da.y = fmaf(-rga.y, ga.y, ga.y);
            da.z = fmaf(-rga.z, ga.z, ga.z); da.w = fmaf(-rga.w, ga.w, ga.w);
            db.x = fmaf(-rgb.x, gb.x, gb.x); db.y = fmaf(-rgb.y, gb.y, gb.y);
            db.z = fmaf(-rgb.z, gb.z, gb.z); db.w = fmaf(-rgb.w, gb.w, gb.w);

            // ---- poll spikes(t-1): waves 0-1, one line per lane,
            // each of the 128 slot lines read once per block per round
            if (wv < 2) {
                const int s = (wv << 6) | k;
                const u64* sl = slots +
                    ((size_t)((t - 1) & 1) * NSLOT + s) * PADU;
                const unsigned want = (unsigned)(t - 1);
                u64 A = __hip_atomic_load(sl, __ATOMIC_RELAXED,
                                          __HIP_MEMORY_SCOPE_AGENT);
                while ((unsigned)(A >> 32) != want) {
                    __builtin_amdgcn_s_sleep(1);
                    A = __hip_atomic_load(sl, __ATOMIC_RELAXED,
                                          __HIP_MEMORY_SCOPE_AGENT);
                }
                sbits[s] = (unsigned)A;   // low 16 bits = block s's spikes
            }
        }
        __syncthreads();  // barrier 1: sbits complete; certifies all 128
                          // slots observed at tag t-1 block-wide

        if (t != 0) {
            const unsigned bits = sbits[slot_i] >> bitbase;  // broadcast read
            ga.x = (bits &   1u) ? 1.0f : da.x;
            ga.y = (bits &   2u) ? 1.0f : da.y;
            ga.z = (bits &   4u) ? 1.0f : da.z;
            ga.w = (bits &   8u) ? 1.0f : da.w;
            gb.x = (bits &  16u) ? 1.0f : db.x;
            gb.y = (bits &  32u) ? 1.0f : db.y;
            gb.z = (bits &  64u) ? 1.0f : db.z;
            gb.w = (bits & 128u) ? 1.0f : db.w;
        }

        // ---- dot: rows 4i..4i+3 x cols 512j+8k..+7, w and g from registers
        float a0 = 0.f, a1 = 0.f, a2 = 0.f, a3 = 0.f;
#define ROWFMA(acc, wa, wb)                                       \
        acc = fmaf(wa.x, ga.x, acc); acc = fmaf(wa.y, ga.y, acc); \
        acc = fmaf(wa.z, ga.z, acc); acc = fmaf(wa.w, ga.w, acc); \
        acc = fmaf(wb.x, gb.x, acc); acc = fmaf(wb.y, gb.y, acc); \
        acc = fmaf(wb.z, gb.z, acc); acc = fmaf(wb.w, gb.w, acc);
        ROWFMA(a0, w0a, w0b)
        ROWFMA(a1, w1a, w1b)
        ROWFMA(a2, w2a, w2b)
        ROWFMA(a3, w3a, w3b)
#undef ROWFMA
        // 64-lane sum via DPP (VALU pipe only; bitwise == old butterfly),
        // result in lane 63
        WAVE_RED(a0)
        WAVE_RED(a1)
        WAVE_RED(a2)
        WAVE_RED(a3)
        if (k == 63)
            ((float4*)preduce[t & 1])[j * 4 + i] = make_float4(a0, a1, a2, a3);
        __syncthreads();  // barrier 2: preduce complete

        // ---- neuron update + spike-bit publish (wave 0, lanes 0..15)
        if (tid < RPB) {
            const float* pr = (const float*)preduce[t & 1];
            float u = (pr[tid] + pr[tid + 16]) + (pr[tid + 32] + pr[tid + 48]);
            float I = post_c * stable_sigmoid(pre_c * (u + x));
            v = v + (vr - v + I) * rtm;
            bool spk = (v >= 30.0f);
            u64 bal = __ballot(spk);   // bits 0..15 = this block's spikes
            if (tid == 0) {
                u64 pk = ((u64)(unsigned)t << 32) | (bal & 0xFFFFull);
                __hip_atomic_store(slots + ((size_t)(t & 1) * NSLOT + b) * PADU,
                                   pk, __ATOMIC_RELAXED,
                                   __HIP_MEMORY_SCOPE_AGENT);
            }
            // keep the expensive soft-sigmoid/LDS writes BELOW the publish
            __builtin_amdgcn_sched_barrier(0);
            float soft = stable_sigmoid(v - 30.0f);   // pre-reset v
            v = spk ? vr : v;
            vbuf[(t >> 6) & 1][t & (DUMP - 1)][tid] = v;
            sbuf[(t >> 6) & 1][t & (DUMP - 1)][tid] = soft;
        }

        // ---- output dump (after the update so it never delays the
        // publish): window closed 64 steps ago, opposite buffer
        if ((t & (DUMP - 1)) == 0 && t != 0) {
            const int bb = ((t >> 6) & 1) ^ 1;
            const int t0 = t - DUMP;
            const int s  = tid >> 4;
            const int rr = tid & 15;
            size_t o = (size_t)(t0 + s) * NN + b * RPB + rr;
            out[o] = vbuf[bb][s][rr];
            out[(size_t)T_STEPS * NN + o] = sbuf[bb][s][rr];
        }
        // no trailing barrier: next sbits write is by waves 0-1 after THEIR
        // barrier-2 arrival; preduce alternates parity; vbuf half-buffers
        // alternate every 64 steps; slot overwrite is 2 steps away.
    }

    // ---- final window dump
    __syncthreads();
    {
        const int bb = ((T_STEPS - DUMP) >> 6) & 1;
        const int t0 = T_STEPS - DUMP;
        const int s  = tid >> 4;
        const int rr = tid & 15;
        size_t o = (size_t)(t0 + s) * NN + b * RPB + rr;
        out[o] = vbuf[bb][s][rr];
        out[(size_t)T_STEPS * NN + o] = sbuf[bb][s][rr];
    }
}

extern "C" void kernel_launch(void* const* d_in, const int* in_sizes, int n_in,
                              void* d_out, int out_size, void* d_ws, size_t ws_size,
                              hipStream_t stream) {
    const float* x_in   = (const float*)d_in[0];
    const float* w      = (const float*)d_in[1];
    const float* v_rest = (const float*)d_in[2];
    const float* tau_m  = (const float*)d_in[3];
    const float* tau_g  = (const float*)d_in[4];
    const float* pre_c  = (const float*)d_in[5];
    const float* post_c = (const float*)d_in[6];
    const float* v0     = (const float*)d_in[7];
    const float* g0     = (const float*)d_in[8];
    float* out = (float*)d_out;

    u64* slots = (u64*)d_ws;  // [2, NSLOT, PADU]

    // tag 0xFFFFFFFF never matches any t in [0, 8192)
    hipMemsetAsync(slots, 0xFF, 2 * NSLOT * PADU * sizeof(u64), stream);

    void* args[] = {
        (void*)&x_in, (void*)&w, (void*)&v_rest, (void*)&tau_m, (void*)&tau_g,
        (void*)&pre_c, (void*)&post_c, (void*)&v0, (void*)&g0,
        (void*)&out, (void*)&slots
    };
    hipLaunchCooperativeKernel((void*)lif_kernel, dim3(NBLK), dim3(NTHR),
                               args, 0, stream);
}